// Round 1
// baseline (385.462 us; speedup 1.0000x reference)
//
#include <hip/hip_runtime.h>
#include <hip/hip_bf16.h>
#include <cstdint>

typedef __bf16 bf16x8 __attribute__((ext_vector_type(8)));
typedef float floatx4 __attribute__((ext_vector_type(4)));

__device__ __forceinline__ void gl2lds16(const void* g, void* l) {
  __builtin_amdgcn_global_load_lds(
      (const __attribute__((address_space(1))) unsigned int*)g,
      (__attribute__((address_space(3))) unsigned int*)(uintptr_t)l,
      16, 0, 0);
}

// ---------------- fp32 -> bf16 convert ----------------
__global__ __launch_bounds__(256)
void cvt_kernel(const float* __restrict__ in, __hip_bfloat16* __restrict__ out, int n) {
  int i = (blockIdx.x * 256 + threadIdx.x) * 4;
  if (i >= n) return;
  const float4 v = *(const float4*)(in + i);
  out[i + 0] = __float2bfloat16(v.x);
  out[i + 1] = __float2bfloat16(v.y);
  out[i + 2] = __float2bfloat16(v.z);
  out[i + 3] = __float2bfloat16(v.w);
}

// ---------------- plain bf16 GEMM (O-proj): C[M][Nc] = A[M][K] * B[Nc][K]^T ----
__global__ __launch_bounds__(256)
void gemm_bt(const __hip_bfloat16* __restrict__ A, const __hip_bfloat16* __restrict__ Bm,
             void* __restrict__ Cp, int M, int Nc, int K, int c_fp32)
{
  __shared__ __hip_bfloat16 As[128 * 32];
  __shared__ __hip_bfloat16 Bs[128 * 32];
  const int tid = threadIdx.x;
  const int lane = tid & 63, wave = tid >> 6;
  const int wm = (wave & 1) * 64, wn = (wave >> 1) * 64;
  const int m0 = blockIdx.x * 128, n0 = blockIdx.y * 128;
  const int lrow = lane & 15, lk = (lane >> 4) * 8;
  floatx4 acc[4][4] = {};
  const int c0 = tid, c1 = tid + 256;
  const int r0 = c0 >> 2, o0 = (c0 & 3) * 8;
  const int r1 = c1 >> 2, o1 = (c1 & 3) * 8;
  for (int kt = 0; kt < K; kt += 32) {
    __syncthreads();
    gl2lds16(A + (size_t)(m0 + r0) * K + kt + o0, &As[c0 * 8]);
    gl2lds16(A + (size_t)(m0 + r1) * K + kt + o1, &As[c1 * 8]);
    gl2lds16(Bm + (size_t)(n0 + r0) * K + kt + o0, &Bs[c0 * 8]);
    gl2lds16(Bm + (size_t)(n0 + r1) * K + kt + o1, &Bs[c1 * 8]);
    __syncthreads();
    bf16x8 af[4], bfr[4];
#pragma unroll
    for (int t = 0; t < 4; t++) af[t] = *(const bf16x8*)&As[(wm + t * 16 + lrow) * 32 + lk];
#pragma unroll
    for (int t = 0; t < 4; t++) bfr[t] = *(const bf16x8*)&Bs[(wn + t * 16 + lrow) * 32 + lk];
#pragma unroll
    for (int mt = 0; mt < 4; mt++)
#pragma unroll
      for (int nt = 0; nt < 4; nt++)
        acc[mt][nt] = __builtin_amdgcn_mfma_f32_16x16x32_bf16(af[mt], bfr[nt], acc[mt][nt], 0, 0, 0);
  }
  const int lq4 = (lane >> 4) * 4;
#pragma unroll
  for (int mt = 0; mt < 4; mt++)
#pragma unroll
    for (int nt = 0; nt < 4; nt++)
#pragma unroll
      for (int r = 0; r < 4; r++) {
        const int m = m0 + wm + mt * 16 + lq4 + r;
        const int n = n0 + wn + nt * 16 + lrow;
        const float v = acc[mt][nt][r];
        if (c_fp32) ((float*)Cp)[(size_t)m * Nc + n] = v;
        else ((__hip_bfloat16*)Cp)[(size_t)m * Nc + n] = __float2bfloat16(v);
      }
}

// ---------------- QKV GEMM with fused RoPE + relayout epilogue ----------------
__global__ __launch_bounds__(256)
void gemm_qkv_fused(const __hip_bfloat16* __restrict__ A,
                    const __hip_bfloat16* __restrict__ W,
                    __hip_bfloat16* __restrict__ Qr,
                    __hip_bfloat16* __restrict__ Kr,
                    __hip_bfloat16* __restrict__ Vt)
{
  __shared__ alignas(16) char smem[16640];     // union: As+Bs (16384) | Cs 64x130 bf16 (16640)
  __shared__ float invf[64];
  __hip_bfloat16* As = (__hip_bfloat16*)smem;
  __hip_bfloat16* Bs = As + 128 * 32;
  __hip_bfloat16* Cs = (__hip_bfloat16*)smem;  // [64][130]
  const int tid = threadIdx.x;
  if (tid < 64) invf[tid] = __expf(-(float)tid * 0.14391156831212787f);  // 10000^(-t/64)
  const int lane = tid & 63, wave = tid >> 6;
  const int wm = (wave & 1) * 64, wn = (wave >> 1) * 64;
  const int m0 = blockIdx.x * 128, n0 = blockIdx.y * 128;
  const int K = 2048;
  const int lrow = lane & 15, lk = (lane >> 4) * 8;
  floatx4 acc[4][4] = {};
  const int c0 = tid, c1 = tid + 256;
  const int r0 = c0 >> 2, o0 = (c0 & 3) * 8;
  const int r1 = c1 >> 2, o1 = (c1 & 3) * 8;
  for (int kt = 0; kt < K; kt += 32) {
    __syncthreads();
    gl2lds16(A + (size_t)(m0 + r0) * K + kt + o0, &As[c0 * 8]);
    gl2lds16(A + (size_t)(m0 + r1) * K + kt + o1, &As[c1 * 8]);
    gl2lds16(W + (size_t)(n0 + r0) * K + kt + o0, &Bs[c0 * 8]);
    gl2lds16(W + (size_t)(n0 + r1) * K + kt + o1, &Bs[c1 * 8]);
    __syncthreads();
    bf16x8 af[4], bfr[4];
#pragma unroll
    for (int t = 0; t < 4; t++) af[t] = *(const bf16x8*)&As[(wm + t * 16 + lrow) * 32 + lk];
#pragma unroll
    for (int t = 0; t < 4; t++) bfr[t] = *(const bf16x8*)&Bs[(wn + t * 16 + lrow) * 32 + lk];
#pragma unroll
    for (int mt = 0; mt < 4; mt++)
#pragma unroll
      for (int nt = 0; nt < 4; nt++)
        acc[mt][nt] = __builtin_amdgcn_mfma_f32_16x16x32_bf16(af[mt], bfr[nt], acc[mt][nt], 0, 0, 0);
  }
  const int lq4 = (lane >> 4) * 4;
  const int seg = n0 >> 11;            // 0=Q 1=K 2=V
  const int h = (n0 & 2047) >> 7;
  const int b = m0 >> 11;
  const int bh = b * 16 + h;
  const int seq0 = m0 & 2047;
  const float qscale = (seg == 0) ? 0.08838834764831845f : 1.0f;
  for (int pass = 0; pass < 2; ++pass) {
    __syncthreads();
    if ((wave & 1) == pass) {
#pragma unroll
      for (int mt = 0; mt < 4; mt++)
#pragma unroll
        for (int nt = 0; nt < 4; nt++)
#pragma unroll
          for (int r = 0; r < 4; r++)
            Cs[(mt * 16 + lq4 + r) * 130 + wn + nt * 16 + lrow] =
                __float2bfloat16(acc[mt][nt][r]);
    }
    __syncthreads();
    if (seg < 2) {
      __hip_bfloat16* Out = seg ? Kr : Qr;
#pragma unroll
      for (int p = 0; p < 2; ++p) {
        const int row = (tid >> 3) + p * 32;
        const int oct = (tid & 7) * 8;
        const int m = m0 + pass * 64 + row;
        const float pos = (float)(m & 2047);
        alignas(16) __hip_bfloat16 lo[8], hi[8];
#pragma unroll
        for (int k2 = 0; k2 < 8; k2++) {
          const float ang = pos * invf[oct + k2];
          float sn, cs2;
          __sincosf(ang, &sn, &cs2);
          const float a  = __bfloat162float(Cs[row * 130 + oct + k2]);
          const float bb = __bfloat162float(Cs[row * 130 + oct + k2 + 64]);
          lo[k2] = __float2bfloat16((a * cs2 - bb * sn) * qscale);
          hi[k2] = __float2bfloat16((bb * cs2 + a * sn) * qscale);
        }
        const size_t ob = ((size_t)bh * 2048 + (size_t)(m & 2047)) * 128;
        *(bf16x8*)&Out[ob + oct]      = *(const bf16x8*)lo;
        *(bf16x8*)&Out[ob + oct + 64] = *(const bf16x8*)hi;
      }
    } else {
#pragma unroll
      for (int p = 0; p < 4; ++p) {
        const int d = (tid >> 3) + p * 32;
        const int s8 = (tid & 7) * 8;
        alignas(16) __hip_bfloat16 tmp[8];
#pragma unroll
        for (int k2 = 0; k2 < 8; k2++) tmp[k2] = Cs[(s8 + k2) * 130 + d];
        const size_t ob = ((size_t)bh * 128 + d) * 2048 + seq0 + pass * 64 + s8;
        *(bf16x8*)&Vt[ob] = *(const bf16x8*)tmp;
      }
    }
  }
}

// ---------------- sliding-window flash attention, pipelined reg->LDS staging ---
// 128 q-rows/block, 8 waves; S^T = K*Q^T; padded LDS strides (no bank conflicts);
// global->reg loads for tile jt+1 issued before a raw (non-vmcnt-draining)
// barrier so they overlap compute of tile jt.
#define KSTR 136   // K tile row stride (elems): 272B -> bank-start lrow*4 (mod 32)
#define VSTR 72    // V/P tile row stride: 144B -> bank-start lrow*4 (mod 32)
__global__ __launch_bounds__(512, 4)
void attn_swa(const __hip_bfloat16* __restrict__ Qr, const __hip_bfloat16* __restrict__ Kr,
              const __hip_bfloat16* __restrict__ Vt, __hip_bfloat16* __restrict__ Out)
{
  __shared__ __hip_bfloat16 Ks[64 * KSTR];
  __shared__ __hip_bfloat16 Vs[128 * VSTR];
  __shared__ __hip_bfloat16 Pb[8][16 * VSTR];
  const int qt = blockIdx.x, bh = blockIdx.y;
  const int tid = threadIdx.x, lane = tid & 63, wave = tid >> 6;
  const int lrow = lane & 15, lk = (lane >> 4) * 8, lq4 = (lane >> 4) * 4;
  const int i0 = qt * 128;
  const float NEG_INF = -__builtin_inff();
  const __hip_bfloat16* Qh = Qr + (size_t)bh * 2048 * 128;
  const __hip_bfloat16* Kh = Kr + (size_t)bh * 2048 * 128;
  const __hip_bfloat16* Vh = Vt + (size_t)bh * 128 * 2048;

  // staging slot assignment (per thread: 2 K granules + 2 V granules)
  const int ck0 = tid, ck1 = tid + 512;          // K slots: row=c>>4, g=c&15
  const int kr0 = ck0 >> 4, kg0 = (ck0 & 15) * 8;
  const int kr1 = ck1 >> 4, kg1 = (ck1 & 15) * 8;
  const int cv0 = tid, cv1 = tid + 512;          // V slots: d=c>>3, col=(c&7)*8
  const int vd0 = cv0 >> 3, vc0 = (cv0 & 7) * 8;
  const int vd1 = cv1 >> 3, vc1 = (cv1 & 7) * 8;

  // Q fragments straight from global (one-time)
  const int iw = i0 + wave * 16 + lrow;          // this lane's q row
  bf16x8 qf[4];
#pragma unroll
  for (int ks = 0; ks < 4; ks++)
    qf[ks] = *(const bf16x8*)&Qh[(size_t)iw * 128 + ks * 32 + lk];

  floatx4 accO[8] = {};
  float m_i = NEG_INF, l_i = 0.f;
  const int imin = i0 + wave * 16;
  const int lo = i0 - 511;
  const int jt_lo = (lo > 0 ? lo : 0) >> 6;
  const int jt_hi = (i0 + 127) >> 6;

  // prefetch tile jt_lo into registers
  int j0n = jt_lo * 64;
  int4 rk0 = *(const int4*)&Kh[(size_t)(j0n + kr0) * 128 + kg0];
  int4 rk1 = *(const int4*)&Kh[(size_t)(j0n + kr1) * 128 + kg1];
  int4 rv0 = *(const int4*)&Vh[(size_t)vd0 * 2048 + j0n + vc0];
  int4 rv1 = *(const int4*)&Vh[(size_t)vd1 * 2048 + j0n + vc1];

  for (int jt = jt_lo; jt <= jt_hi; jt++) {
    const int j0 = jt * 64;
    __syncthreads();  // all waves done reading prev tile; drains vmcnt -> regs ready
    *(int4*)&Ks[kr0 * KSTR + kg0] = rk0;
    *(int4*)&Ks[kr1 * KSTR + kg1] = rk1;
    *(int4*)&Vs[vd0 * VSTR + vc0] = rv0;
    *(int4*)&Vs[vd1 * VSTR + vc1] = rv1;
    if (jt < jt_hi) {  // issue next tile's loads; they stay in flight through compute
      const int jn = j0 + 64;
      rk0 = *(const int4*)&Kh[(size_t)(jn + kr0) * 128 + kg0];
      rk1 = *(const int4*)&Kh[(size_t)(jn + kr1) * 128 + kg1];
      rv0 = *(const int4*)&Vh[(size_t)vd0 * 2048 + jn + vc0];
      rv1 = *(const int4*)&Vh[(size_t)vd1 * 2048 + jn + vc1];
    }
    // raw barrier: wait LDS writes only (lgkmcnt(0)), leave vmcnt in flight
    asm volatile("" ::: "memory");
    __builtin_amdgcn_s_waitcnt(0xC07F);  // vmcnt=max, expcnt=max, lgkmcnt=0
    __builtin_amdgcn_s_barrier();
    asm volatile("" ::: "memory");

    // S^T[j][i] = sum_d K[j][d] Q[i][d]
    floatx4 s[4] = {};
#pragma unroll
    for (int nt = 0; nt < 4; nt++) {
      const int krow = (nt * 16 + lrow) * KSTR;
#pragma unroll
      for (int ks = 0; ks < 4; ks++) {
        const bf16x8 kf = *(const bf16x8*)&Ks[krow + ks * 32 + lk];
        s[nt] = __builtin_amdgcn_mfma_f32_16x16x32_bf16(kf, qf[ks], s[nt], 0, 0, 0);
      }
    }
    // lane holds: i = iw (fixed), j = j0 + nt*16 + lq4 + r
    const bool full = (j0 + 63 <= imin) && (j0 >= imin + 15 - 511);
    float rmax = NEG_INF;
    if (full) {
#pragma unroll
      for (int nt = 0; nt < 4; nt++)
#pragma unroll
        for (int r = 0; r < 4; r++) rmax = fmaxf(rmax, s[nt][r]);
    } else {
#pragma unroll
      for (int nt = 0; nt < 4; nt++) {
#pragma unroll
        for (int r = 0; r < 4; r++) {
          const int j = j0 + nt * 16 + lq4 + r;
          const float sv = ((j <= iw) && (j > iw - 512)) ? s[nt][r] : NEG_INF;
          s[nt][r] = sv;
          rmax = fmaxf(rmax, sv);
        }
      }
    }
    rmax = fmaxf(rmax, __shfl_xor(rmax, 16));
    rmax = fmaxf(rmax, __shfl_xor(rmax, 32));
    const float mnew = fmaxf(m_i, rmax);
    const float alpha = __expf(fminf(m_i - mnew, 0.f));  // guards (-inf)-(-inf)
    m_i = mnew;
    float rs = 0.f;
    if (full) {
#pragma unroll
      for (int nt = 0; nt < 4; nt++)
#pragma unroll
        for (int r = 0; r < 4; r++) {
          const float p = __expf(s[nt][r] - mnew);
          s[nt][r] = p;
          rs += p;
        }
    } else {
#pragma unroll
      for (int nt = 0; nt < 4; nt++)
#pragma unroll
        for (int r = 0; r < 4; r++) {
          const float sv = s[nt][r];
          const float p = (sv == NEG_INF) ? 0.f : __expf(sv - mnew);
          s[nt][r] = p;
          rs += p;
        }
    }
    rs += __shfl_xor(rs, 16);
    rs += __shfl_xor(rs, 32);
    l_i = l_i * alpha + rs;
#pragma unroll
    for (int dt = 0; dt < 8; dt++) accO[dt] *= alpha;
    // P^T -> Pb[i][j] packed b64 (wave-private; same-wave LDS ops ordered)
#pragma unroll
    for (int nt = 0; nt < 4; nt++) {
      alignas(8) __hip_bfloat16 p4[4];
#pragma unroll
      for (int r = 0; r < 4; r++) p4[r] = __float2bfloat16(s[nt][r]);
      *(uint64_t*)&Pb[wave][lrow * VSTR + nt * 16 + lq4] = *(const uint64_t*)p4;
    }
    bf16x8 pf[2];
#pragma unroll
    for (int jf = 0; jf < 2; jf++)
      pf[jf] = *(const bf16x8*)&Pb[wave][lrow * VSTR + jf * 32 + lk];
    // O^T[d][i] += sum_j V^T[d][j] P[i][j]
#pragma unroll
    for (int dt = 0; dt < 8; dt++) {
      const int vrow = (dt * 16 + lrow) * VSTR;
#pragma unroll
      for (int jf = 0; jf < 2; jf++) {
        const bf16x8 vf = *(const bf16x8*)&Vs[vrow + jf * 32 + lk];
        accO[dt] = __builtin_amdgcn_mfma_f32_16x16x32_bf16(vf, pf[jf], accO[dt], 0, 0, 0);
      }
    }
  }
  // write: lane has O^T[d = dt*16+lq4+r][i = iw]; pack 4 consecutive d as 8B
  const int b = bh >> 4, h = bh & 15;
  const float inv_l = 1.0f / l_i;
  const size_t rowb = ((size_t)(b * 2048 + iw)) * 2048 + h * 128;
#pragma unroll
  for (int dt = 0; dt < 8; dt++) {
    alignas(8) __hip_bfloat16 o4[4];
#pragma unroll
    for (int r = 0; r < 4; r++) o4[r] = __float2bfloat16(accO[dt][r] * inv_l);
    *(uint64_t*)&Out[rowb + dt * 16 + lq4] = *(const uint64_t*)o4;
  }
}

// ---------------- launch ----------------
extern "C" void kernel_launch(void* const* d_in, const int* in_sizes, int n_in,
                              void* d_out, int out_size, void* d_ws, size_t ws_size,
                              hipStream_t stream)
{
  const float* x = (const float*)d_in[0];      // [2,2048,2048]
  const float* w_qkv = (const float*)d_in[1];  // [6144,2048]
  const float* w_o = (const float*)d_in[2];    // [2048,2048]
  float* y = (float*)d_out;                    // [2,2048,2048] fp32
  char* ws = (char*)d_ws;

  const size_t SZ_X = 16777216;     // 4096*2048*2 B
  const size_t SZ_WQKV = 25165824;  // 6144*2048*2 B
  const size_t SZ_Q = 16777216;     // 32*2048*128*2 B

  __hip_bfloat16* xb = (__hip_bfloat16*)(ws);            // x bf16; later attn out
  __hip_bfloat16* wqkvb = (__hip_bfloat16*)(ws + SZ_X);  // w_qkv bf16; later w_o bf16
  __hip_bfloat16* Qr = (__hip_bfloat16*)(ws + SZ_X + SZ_WQKV);
  __hip_bfloat16* Kr = (__hip_bfloat16*)(ws + SZ_X + SZ_WQKV + SZ_Q);
  __hip_bfloat16* Vt = (__hip_bfloat16*)(ws + SZ_X + SZ_WQKV + 2 * SZ_Q);

  cvt_kernel<<<dim3(8192), dim3(256), 0, stream>>>(x, xb, 8388608);
  cvt_kernel<<<dim3(12288), dim3(256), 0, stream>>>(w_qkv, wqkvb, 12582912);
  gemm_qkv_fused<<<dim3(32, 48), dim3(256), 0, stream>>>(xb, wqkvb, Qr, Kr, Vt);
  attn_swa<<<dim3(16, 32), dim3(512), 0, stream>>>(Qr, Kr, Vt, xb /*attn_out*/);
  cvt_kernel<<<dim3(4096), dim3(256), 0, stream>>>(w_o, wqkvb, 4194304);
  gemm_bt<<<dim3(32, 16), dim3(256), 0, stream>>>(xb, wqkvb, (void*)y, 4096, 2048, 2048, 1);
}

// Round 2
// 363.531 us; speedup vs baseline: 1.0603x; 1.0603x over previous
//
#include <hip/hip_runtime.h>
#include <hip/hip_bf16.h>
#include <cstdint>

typedef __bf16 bf16x8 __attribute__((ext_vector_type(8)));
typedef float floatx4 __attribute__((ext_vector_type(4)));

__device__ __forceinline__ void gl2lds16(const void* g, void* l) {
  __builtin_amdgcn_global_load_lds(
      (const __attribute__((address_space(1))) unsigned int*)g,
      (__attribute__((address_space(3))) unsigned int*)(uintptr_t)l,
      16, 0, 0);
}

// ---------------- fp32 -> bf16 convert ----------------
__global__ __launch_bounds__(256)
void cvt_kernel(const float* __restrict__ in, __hip_bfloat16* __restrict__ out, int n) {
  int i = (blockIdx.x * 256 + threadIdx.x) * 4;
  if (i >= n) return;
  const float4 v = *(const float4*)(in + i);
  out[i + 0] = __float2bfloat16(v.x);
  out[i + 1] = __float2bfloat16(v.y);
  out[i + 2] = __float2bfloat16(v.z);
  out[i + 3] = __float2bfloat16(v.w);
}

// ---------------- plain bf16 GEMM (O-proj): C[M][Nc] = A[M][K] * B[Nc][K]^T ----
__global__ __launch_bounds__(256)
void gemm_bt(const __hip_bfloat16* __restrict__ A, const __hip_bfloat16* __restrict__ Bm,
             void* __restrict__ Cp, int M, int Nc, int K, int c_fp32)
{
  __shared__ __hip_bfloat16 As[128 * 32];
  __shared__ __hip_bfloat16 Bs[128 * 32];
  const int tid = threadIdx.x;
  const int lane = tid & 63, wave = tid >> 6;
  const int wm = (wave & 1) * 64, wn = (wave >> 1) * 64;
  const int m0 = blockIdx.x * 128, n0 = blockIdx.y * 128;
  const int lrow = lane & 15, lk = (lane >> 4) * 8;
  floatx4 acc[4][4] = {};
  const int c0 = tid, c1 = tid + 256;
  const int r0 = c0 >> 2, o0 = (c0 & 3) * 8;
  const int r1 = c1 >> 2, o1 = (c1 & 3) * 8;
  for (int kt = 0; kt < K; kt += 32) {
    __syncthreads();
    gl2lds16(A + (size_t)(m0 + r0) * K + kt + o0, &As[c0 * 8]);
    gl2lds16(A + (size_t)(m0 + r1) * K + kt + o1, &As[c1 * 8]);
    gl2lds16(Bm + (size_t)(n0 + r0) * K + kt + o0, &Bs[c0 * 8]);
    gl2lds16(Bm + (size_t)(n0 + r1) * K + kt + o1, &Bs[c1 * 8]);
    __syncthreads();
    bf16x8 af[4], bfr[4];
#pragma unroll
    for (int t = 0; t < 4; t++) af[t] = *(const bf16x8*)&As[(wm + t * 16 + lrow) * 32 + lk];
#pragma unroll
    for (int t = 0; t < 4; t++) bfr[t] = *(const bf16x8*)&Bs[(wn + t * 16 + lrow) * 32 + lk];
#pragma unroll
    for (int mt = 0; mt < 4; mt++)
#pragma unroll
      for (int nt = 0; nt < 4; nt++)
        acc[mt][nt] = __builtin_amdgcn_mfma_f32_16x16x32_bf16(af[mt], bfr[nt], acc[mt][nt], 0, 0, 0);
  }
  const int lq4 = (lane >> 4) * 4;
#pragma unroll
  for (int mt = 0; mt < 4; mt++)
#pragma unroll
    for (int nt = 0; nt < 4; nt++)
#pragma unroll
      for (int r = 0; r < 4; r++) {
        const int m = m0 + wm + mt * 16 + lq4 + r;
        const int n = n0 + wn + nt * 16 + lrow;
        const float v = acc[mt][nt][r];
        if (c_fp32) ((float*)Cp)[(size_t)m * Nc + n] = v;
        else ((__hip_bfloat16*)Cp)[(size_t)m * Nc + n] = __float2bfloat16(v);
      }
}

// ---------------- QKV GEMM: 256x256 tile, BK=32, quad-buffer depth-3 prefetch ---
// 8 waves (2M x 4N); counted vmcnt (never 0 in main loop); 1 barrier / K-step;
// XOR granule swizzle: LDS slot s holds source granule s ^ ((row>>1)&3)
// -> ds_read_b128 bank conflicts 8-way -> 2-way (free).
// Fused RoPE + relayout epilogue staged through the 128KB LDS.
__global__ __launch_bounds__(512, 2)
void gemm_qkv256(const __hip_bfloat16* __restrict__ A,
                 const __hip_bfloat16* __restrict__ W,
                 __hip_bfloat16* __restrict__ Qr,
                 __hip_bfloat16* __restrict__ Kr,
                 __hip_bfloat16* __restrict__ Vt)
{
  extern __shared__ __hip_bfloat16 sm[];   // 4 bufs x (A 8192 + B 8192) elems = 128KB
  const int tid = threadIdx.x, lane = tid & 63, wave = tid >> 6;
  const int wr = wave >> 2, wc = wave & 3;           // 2 x 4 wave grid
  const int m0 = blockIdx.x << 8, n0 = blockIdx.y << 8;
  const int lrow = lane & 15, dg = lane >> 4, lq4 = dg * 4;
  const int rslot = (dg ^ ((lrow >> 1) & 3)) * 8;    // swizzled read slot (elems)

  // staging map: granule g in [0,1024): row = g>>2, lds slot = g&3,
  // source granule = slot ^ ((row>>1)&3)
  const int arow = tid >> 2;
  const int ascol = ((tid & 3) ^ ((tid >> 3) & 3)) * 8;
  const __hip_bfloat16* aS0 = A + (size_t)(m0 + arow) * 2048 + ascol;
  const __hip_bfloat16* aS1 = A + (size_t)(m0 + 128 + arow) * 2048 + ascol;
  const __hip_bfloat16* bS0 = W + (size_t)(n0 + arow) * 2048 + ascol;
  const __hip_bfloat16* bS1 = W + (size_t)(n0 + 128 + arow) * 2048 + ascol;

  floatx4 acc[8][4] = {};

#define STAGE(TT) do {                                        \
    const int bb_ = (TT) & 3; const int kk_ = (TT) * 32;      \
    gl2lds16(aS0 + kk_, &sm[bb_ * 16384 + tid * 8]);          \
    gl2lds16(aS1 + kk_, &sm[bb_ * 16384 + 4096 + tid * 8]);   \
    gl2lds16(bS0 + kk_, &sm[bb_ * 16384 + 8192 + tid * 8]);   \
    gl2lds16(bS1 + kk_, &sm[bb_ * 16384 + 12288 + tid * 8]);  \
  } while (0)

  STAGE(0); STAGE(1); STAGE(2);   // depth-3 prologue (12 VMEM in flight)

#define KSTEP(TT, WIMM, DOSTAGE) do {                                          \
    asm volatile("" ::: "memory");                                             \
    __builtin_amdgcn_s_waitcnt(WIMM);   /* my tile-TT loads landed; lgkm 0 */  \
    __builtin_amdgcn_s_barrier();       /* everyone's landed; prev reads done */\
    asm volatile("" ::: "memory");                                             \
    const int bb = (TT) & 3;                                                   \
    if (DOSTAGE) STAGE((TT) + 3);                                              \
    bf16x8 af[8], bfr[4];                                                      \
    _Pragma("unroll")                                                          \
    for (int mt = 0; mt < 8; mt++)                                             \
      af[mt] = *(const bf16x8*)&sm[bb * 16384 + (wr * 128 + mt * 16 + lrow) * 32 + rslot]; \
    _Pragma("unroll")                                                          \
    for (int nt = 0; nt < 4; nt++)                                             \
      bfr[nt] = *(const bf16x8*)&sm[bb * 16384 + 8192 + (wc * 64 + nt * 16 + lrow) * 32 + rslot]; \
    __builtin_amdgcn_s_setprio(1);                                             \
    _Pragma("unroll")                                                          \
    for (int mt = 0; mt < 8; mt++)                                             \
      _Pragma("unroll")                                                        \
      for (int nt = 0; nt < 4; nt++)                                           \
        acc[mt][nt] = __builtin_amdgcn_mfma_f32_16x16x32_bf16(af[mt], bfr[nt], acc[mt][nt], 0, 0, 0); \
    __builtin_amdgcn_s_setprio(0);                                             \
  } while (0)

  // waitcnt imms: vmcnt(8)=0x78, vmcnt(4)=0x74, vmcnt(0)=0x70 (all lgkmcnt(0), expcnt max)
  for (int t = 0; t < 61; ++t) KSTEP(t, 0x78, true);   // stages tiles 3..63
  KSTEP(61, 0x78, false);
  KSTEP(62, 0x74, false);
  KSTEP(63, 0x70, false);
#undef KSTEP
#undef STAGE

  // -------- fused epilogue: RoPE (Q/K) or transpose (V), via LDS restage --------
  const int seg = n0 >> 11;               // 0=Q 1=K 2=V
  const int h0 = (n0 & 2047) >> 7;        // first of 2 heads covered by this n-tile
  const int b = m0 >> 11;
  const int seq0 = m0 & 2047;
  float* invfp = (float*)((char*)sm + 122880);   // above Csh/CshT regions

  __syncthreads();                        // all K-loop LDS reads complete
  if (seg < 2 && tid < 64) invfp[tid] = __expf(-(float)tid * 0.14391156831212787f);

  const float qs = (seg == 0) ? 0.08838834764831845f : 1.0f;
  for (int p = 0; p < 2; ++p) {
    if (p) __syncthreads();               // pass-0 reads done before overwrite
    if (wr == p) {
      if (seg < 2) {                      // Csh[row(128)][264] row-major
#pragma unroll
        for (int mt = 0; mt < 8; mt++)
#pragma unroll
          for (int nt = 0; nt < 4; nt++)
#pragma unroll
            for (int r = 0; r < 4; r++)
              sm[(mt * 16 + lq4 + r) * 264 + wc * 64 + nt * 16 + lrow] =
                  __float2bfloat16(acc[mt][nt][r]);
      } else {                            // CshT[col(256)][136] transposed scatter
#pragma unroll
        for (int mt = 0; mt < 8; mt++)
#pragma unroll
          for (int nt = 0; nt < 4; nt++)
#pragma unroll
            for (int r = 0; r < 4; r++)
              sm[(wc * 64 + nt * 16 + lrow) * 136 + mt * 16 + lq4 + r] =
                  __float2bfloat16(acc[mt][nt][r]);
      }
    }
    __syncthreads();
    if (seg < 2) {
      __hip_bfloat16* Out = seg ? Kr : Qr;
#pragma unroll
      for (int it = 0; it < 4; ++it) {
        const int task = tid + it * 512;        // 2048 tasks: 128 rows x 2 heads x 8 grp
        const int row = task >> 4;
        const int hh = (task >> 3) & 1;
        const int g8 = (task & 7) * 8;
        const int seq = seq0 + p * 128 + row;
        const float pos = (float)seq;
        const bf16x8 lo8 = *(const bf16x8*)&sm[row * 264 + hh * 128 + g8];
        const bf16x8 hi8 = *(const bf16x8*)&sm[row * 264 + hh * 128 + g8 + 64];
        alignas(16) __hip_bfloat16 lo[8], hi[8];
#pragma unroll
        for (int k = 0; k < 8; k++) {
          float sn, cs;
          __sincosf(pos * invfp[g8 + k], &sn, &cs);
          const float a = (float)lo8[k];
          const float bb2 = (float)hi8[k];
          lo[k] = __float2bfloat16((a * cs - bb2 * sn) * qs);
          hi[k] = __float2bfloat16((bb2 * cs + a * sn) * qs);
        }
        const size_t ob = ((size_t)((b * 16 + h0 + hh) * 2048 + seq)) * 128;
        *(bf16x8*)&Out[ob + g8] = *(const bf16x8*)lo;
        *(bf16x8*)&Out[ob + g8 + 64] = *(const bf16x8*)hi;
      }
    } else {
#pragma unroll
      for (int it = 0; it < 8; ++it) {
        const int task = tid + it * 512;        // 4096 tasks: 256 cols x 16 seq-grp
        const int col = task >> 4;
        const int sg = (task & 15) * 8;
        const bf16x8 v8 = *(const bf16x8*)&sm[col * 136 + sg];
        const int hh = col >> 7, d = col & 127;
        *(bf16x8*)&Vt[((size_t)((b * 16 + h0 + hh) * 128 + d)) * 2048 + seq0 + p * 128 + sg] = v8;
      }
    }
  }
}

// ---------------- sliding-window flash attention, pipelined reg->LDS staging ---
#define KSTR 136   // K tile row stride (elems): 272B -> bank-start lrow*4 (mod 32)
#define VSTR 72    // V/P tile row stride: 144B -> bank-start lrow*4 (mod 32)
__global__ __launch_bounds__(512, 4)
void attn_swa(const __hip_bfloat16* __restrict__ Qr, const __hip_bfloat16* __restrict__ Kr,
              const __hip_bfloat16* __restrict__ Vt, __hip_bfloat16* __restrict__ Out)
{
  __shared__ __hip_bfloat16 Ks[64 * KSTR];
  __shared__ __hip_bfloat16 Vs[128 * VSTR];
  __shared__ __hip_bfloat16 Pb[8][16 * VSTR];
  const int qt = blockIdx.x, bh = blockIdx.y;
  const int tid = threadIdx.x, lane = tid & 63, wave = tid >> 6;
  const int lrow = lane & 15, lk = (lane >> 4) * 8, lq4 = (lane >> 4) * 4;
  const int i0 = qt * 128;
  const float NEG_INF = -__builtin_inff();
  const __hip_bfloat16* Qh = Qr + (size_t)bh * 2048 * 128;
  const __hip_bfloat16* Kh = Kr + (size_t)bh * 2048 * 128;
  const __hip_bfloat16* Vh = Vt + (size_t)bh * 128 * 2048;

  const int ck0 = tid, ck1 = tid + 512;
  const int kr0 = ck0 >> 4, kg0 = (ck0 & 15) * 8;
  const int kr1 = ck1 >> 4, kg1 = (ck1 & 15) * 8;
  const int cv0 = tid, cv1 = tid + 512;
  const int vd0 = cv0 >> 3, vc0 = (cv0 & 7) * 8;
  const int vd1 = cv1 >> 3, vc1 = (cv1 & 7) * 8;

  const int iw = i0 + wave * 16 + lrow;
  bf16x8 qf[4];
#pragma unroll
  for (int ks = 0; ks < 4; ks++)
    qf[ks] = *(const bf16x8*)&Qh[(size_t)iw * 128 + ks * 32 + lk];

  floatx4 accO[8] = {};
  float m_i = NEG_INF, l_i = 0.f;
  const int imin = i0 + wave * 16;
  const int lo = i0 - 511;
  const int jt_lo = (lo > 0 ? lo : 0) >> 6;
  const int jt_hi = (i0 + 127) >> 6;

  int j0n = jt_lo * 64;
  int4 rk0 = *(const int4*)&Kh[(size_t)(j0n + kr0) * 128 + kg0];
  int4 rk1 = *(const int4*)&Kh[(size_t)(j0n + kr1) * 128 + kg1];
  int4 rv0 = *(const int4*)&Vh[(size_t)vd0 * 2048 + j0n + vc0];
  int4 rv1 = *(const int4*)&Vh[(size_t)vd1 * 2048 + j0n + vc1];

  for (int jt = jt_lo; jt <= jt_hi; jt++) {
    const int j0 = jt * 64;
    __syncthreads();
    *(int4*)&Ks[kr0 * KSTR + kg0] = rk0;
    *(int4*)&Ks[kr1 * KSTR + kg1] = rk1;
    *(int4*)&Vs[vd0 * VSTR + vc0] = rv0;
    *(int4*)&Vs[vd1 * VSTR + vc1] = rv1;
    if (jt < jt_hi) {
      const int jn = j0 + 64;
      rk0 = *(const int4*)&Kh[(size_t)(jn + kr0) * 128 + kg0];
      rk1 = *(const int4*)&Kh[(size_t)(jn + kr1) * 128 + kg1];
      rv0 = *(const int4*)&Vh[(size_t)vd0 * 2048 + jn + vc0];
      rv1 = *(const int4*)&Vh[(size_t)vd1 * 2048 + jn + vc1];
    }
    asm volatile("" ::: "memory");
    __builtin_amdgcn_s_waitcnt(0xC07F);
    __builtin_amdgcn_s_barrier();
    asm volatile("" ::: "memory");

    floatx4 s[4] = {};
#pragma unroll
    for (int nt = 0; nt < 4; nt++) {
      const int krow = (nt * 16 + lrow) * KSTR;
#pragma unroll
      for (int ks = 0; ks < 4; ks++) {
        const bf16x8 kf = *(const bf16x8*)&Ks[krow + ks * 32 + lk];
        s[nt] = __builtin_amdgcn_mfma_f32_16x16x32_bf16(kf, qf[ks], s[nt], 0, 0, 0);
      }
    }
    const bool full = (j0 + 63 <= imin) && (j0 >= imin + 15 - 511);
    float rmax = NEG_INF;
    if (full) {
#pragma unroll
      for (int nt = 0; nt < 4; nt++)
#pragma unroll
        for (int r = 0; r < 4; r++) rmax = fmaxf(rmax, s[nt][r]);
    } else {
#pragma unroll
      for (int nt = 0; nt < 4; nt++) {
#pragma unroll
        for (int r = 0; r < 4; r++) {
          const int j = j0 + nt * 16 + lq4 + r;
          const float sv = ((j <= iw) && (j > iw - 512)) ? s[nt][r] : NEG_INF;
          s[nt][r] = sv;
          rmax = fmaxf(rmax, sv);
        }
      }
    }
    rmax = fmaxf(rmax, __shfl_xor(rmax, 16));
    rmax = fmaxf(rmax, __shfl_xor(rmax, 32));
    const float mnew = fmaxf(m_i, rmax);
    const float alpha = __expf(fminf(m_i - mnew, 0.f));
    m_i = mnew;
    float rs = 0.f;
    if (full) {
#pragma unroll
      for (int nt = 0; nt < 4; nt++)
#pragma unroll
        for (int r = 0; r < 4; r++) {
          const float p = __expf(s[nt][r] - mnew);
          s[nt][r] = p;
          rs += p;
        }
    } else {
#pragma unroll
      for (int nt = 0; nt < 4; nt++)
#pragma unroll
        for (int r = 0; r < 4; r++) {
          const float sv = s[nt][r];
          const float p = (sv == NEG_INF) ? 0.f : __expf(sv - mnew);
          s[nt][r] = p;
          rs += p;
        }
    }
    rs += __shfl_xor(rs, 16);
    rs += __shfl_xor(rs, 32);
    l_i = l_i * alpha + rs;
#pragma unroll
    for (int dt = 0; dt < 8; dt++) accO[dt] *= alpha;
#pragma unroll
    for (int nt = 0; nt < 4; nt++) {
      alignas(8) __hip_bfloat16 p4[4];
#pragma unroll
      for (int r = 0; r < 4; r++) p4[r] = __float2bfloat16(s[nt][r]);
      *(uint64_t*)&Pb[wave][lrow * VSTR + nt * 16 + lq4] = *(const uint64_t*)p4;
    }
    bf16x8 pf[2];
#pragma unroll
    for (int jf = 0; jf < 2; jf++)
      pf[jf] = *(const bf16x8*)&Pb[wave][lrow * VSTR + jf * 32 + lk];
#pragma unroll
    for (int dt = 0; dt < 8; dt++) {
      const int vrow = (dt * 16 + lrow) * VSTR;
#pragma unroll
      for (int jf = 0; jf < 2; jf++) {
        const bf16x8 vf = *(const bf16x8*)&Vs[vrow + jf * 32 + lk];
        accO[dt] = __builtin_amdgcn_mfma_f32_16x16x32_bf16(vf, pf[jf], accO[dt], 0, 0, 0);
      }
    }
  }
  const int b = bh >> 4, h = bh & 15;
  const float inv_l = 1.0f / l_i;
  const size_t rowb = ((size_t)(b * 2048 + iw)) * 2048 + h * 128;
#pragma unroll
  for (int dt = 0; dt < 8; dt++) {
    alignas(8) __hip_bfloat16 o4[4];
#pragma unroll
    for (int r = 0; r < 4; r++) o4[r] = __float2bfloat16(accO[dt][r] * inv_l);
    *(uint64_t*)&Out[rowb + dt * 16 + lq4] = *(const uint64_t*)o4;
  }
}

// ---------------- launch ----------------
extern "C" void kernel_launch(void* const* d_in, const int* in_sizes, int n_in,
                              void* d_out, int out_size, void* d_ws, size_t ws_size,
                              hipStream_t stream)
{
  const float* x = (const float*)d_in[0];      // [2,2048,2048]
  const float* w_qkv = (const float*)d_in[1];  // [6144,2048]
  const float* w_o = (const float*)d_in[2];    // [2048,2048]
  float* y = (float*)d_out;                    // [2,2048,2048] fp32
  char* ws = (char*)d_ws;

  const size_t SZ_X = 16777216;     // 4096*2048*2 B
  const size_t SZ_WQKV = 25165824;  // 6144*2048*2 B
  const size_t SZ_Q = 16777216;     // 32*2048*128*2 B

  __hip_bfloat16* xb = (__hip_bfloat16*)(ws);            // x bf16; later attn out
  __hip_bfloat16* wqkvb = (__hip_bfloat16*)(ws + SZ_X);  // w_qkv bf16; later w_o bf16
  __hip_bfloat16* Qr = (__hip_bfloat16*)(ws + SZ_X + SZ_WQKV);
  __hip_bfloat16* Kr = (__hip_bfloat16*)(ws + SZ_X + SZ_WQKV + SZ_Q);
  __hip_bfloat16* Vt = (__hip_bfloat16*)(ws + SZ_X + SZ_WQKV + 2 * SZ_Q);

  static bool s_attr_done = false;
  if (!s_attr_done) {
    hipFuncSetAttribute((const void*)gemm_qkv256,
                        hipFuncAttributeMaxDynamicSharedMemorySize, 131072);
    s_attr_done = true;
  }

  cvt_kernel<<<dim3(8192), dim3(256), 0, stream>>>(x, xb, 8388608);
  cvt_kernel<<<dim3(12288), dim3(256), 0, stream>>>(w_qkv, wqkvb, 12582912);
  gemm_qkv256<<<dim3(16, 24), dim3(512), 131072, stream>>>(xb, wqkvb, Qr, Kr, Vt);
  attn_swa<<<dim3(16, 32), dim3(512), 0, stream>>>(Qr, Kr, Vt, xb /*attn_out*/);
  cvt_kernel<<<dim3(4096), dim3(256), 0, stream>>>(w_o, wqkvb, 4194304);
  gemm_bt<<<dim3(32, 16), dim3(256), 0, stream>>>(xb, wqkvb, (void*)y, 4096, 2048, 2048, 1);
}

// Round 4
// 361.181 us; speedup vs baseline: 1.0672x; 1.0065x over previous
//
#include <hip/hip_runtime.h>
#include <hip/hip_bf16.h>
#include <cstdint>

typedef __bf16 bf16x8 __attribute__((ext_vector_type(8)));
typedef float floatx4 __attribute__((ext_vector_type(4)));

__device__ __forceinline__ void gl2lds16(const void* g, void* l) {
  __builtin_amdgcn_global_load_lds(
      (const __attribute__((address_space(1))) unsigned int*)g,
      (__attribute__((address_space(3))) unsigned int*)(uintptr_t)l,
      16, 0, 0);
}

// ---------------- fp32 -> bf16 convert ----------------
__global__ __launch_bounds__(256)
void cvt_kernel(const float* __restrict__ in, __hip_bfloat16* __restrict__ out, int n) {
  int i = (blockIdx.x * 256 + threadIdx.x) * 4;
  if (i >= n) return;
  const float4 v = *(const float4*)(in + i);
  out[i + 0] = __float2bfloat16(v.x);
  out[i + 1] = __float2bfloat16(v.y);
  out[i + 2] = __float2bfloat16(v.z);
  out[i + 3] = __float2bfloat16(v.w);
}

// ================= shared 256x256 2-phase K-loop machinery =================
// 8 waves (2M x 4N); quad-buffer BK=32, depth-3 prefetch; counted vmcnt (never
// 0 in steady loop). Per K-step:
//   waitcnt vmcnt(8) -> barrier0 (ALL waves' tile-TT staging landed; all
//   prev-step reads drained) -> {ds_read A0+B | STAGE_A} -> barrier1 ->
//   lgkm(0) -> MFMA-A -> barrier2 -> {ds_read A1 | STAGE_B} -> barrier3 ->
//   lgkm(0) -> MFMA-B -> (next step's barrier0).
// XOR granule swizzle: LDS slot s of row r holds source granule s ^ ((r>>1)&3).

#define GEMM_PREAMBLE(APTR, BPTR)                                              \
  const int tid = threadIdx.x, lane = tid & 63, wave = tid >> 6;               \
  const int wr = wave >> 2, wc = wave & 3;                                     \
  const int m0 = blockIdx.x << 8, n0 = blockIdx.y << 8;                        \
  const int lrow = lane & 15, dg = lane >> 4, lq4 = dg * 4;                    \
  const int rslot = (dg ^ ((lrow >> 1) & 3)) * 8;                              \
  const int arow = tid >> 2;                                                   \
  const int ascol = ((tid & 3) ^ ((tid >> 3) & 3)) * 8;                        \
  const __hip_bfloat16* aS0 = (APTR) + (size_t)(m0 + arow) * 2048 + ascol;     \
  const __hip_bfloat16* aS1 = (APTR) + (size_t)(m0 + 128 + arow) * 2048 + ascol; \
  const __hip_bfloat16* bS0 = (BPTR) + (size_t)(n0 + arow) * 2048 + ascol;     \
  const __hip_bfloat16* bS1 = (BPTR) + (size_t)(n0 + 128 + arow) * 2048 + ascol; \
  floatx4 acc[8][4] = {};

#define STAGE_A(TT) do { const int bb_ = (TT) & 3; const int kk_ = (TT) * 32;  \
    gl2lds16(aS0 + kk_, &sm[bb_ * 16384 + tid * 8]);                           \
    gl2lds16(aS1 + kk_, &sm[bb_ * 16384 + 4096 + tid * 8]); } while (0)
#define STAGE_B(TT) do { const int bb_ = (TT) & 3; const int kk_ = (TT) * 32;  \
    gl2lds16(bS0 + kk_, &sm[bb_ * 16384 + 8192 + tid * 8]);                    \
    gl2lds16(bS1 + kk_, &sm[bb_ * 16384 + 12288 + tid * 8]); } while (0)

#define STAGE_AB(TT) do { STAGE_A(TT); STAGE_B(TT); } while (0)

#define MEMFENCE asm volatile("" ::: "memory")

// waitcnt imms: 0x0078 = vmcnt(8) lgkm(0); 0x0074 = vmcnt(4) lgkm(0);
//               0x0070 = vmcnt(0) lgkm(0); 0xC07F = vmcnt(max) lgkm(0)
#define KSTEP(TT, WIMM, DOSTAGE) do {                                          \
    const int bb = (TT) & 3;                                                   \
    MEMFENCE; __builtin_amdgcn_s_waitcnt(WIMM); MEMFENCE;                      \
    __builtin_amdgcn_s_barrier();  /* barrier0: all tile-TT staged */          \
    MEMFENCE;                                                                  \
    bf16x8 af0[4], af1[4], bfr[4];                                             \
    _Pragma("unroll")                                                          \
    for (int mt = 0; mt < 4; mt++)                                             \
      af0[mt] = *(const bf16x8*)&sm[bb * 16384 + (wr * 128 + mt * 16 + lrow) * 32 + rslot]; \
    _Pragma("unroll")                                                          \
    for (int nt = 0; nt < 4; nt++)                                             \
      bfr[nt] = *(const bf16x8*)&sm[bb * 16384 + 8192 + (wc * 64 + nt * 16 + lrow) * 32 + rslot]; \
    if (DOSTAGE) STAGE_A((TT) + 3);                                            \
    MEMFENCE; __builtin_amdgcn_s_barrier(); MEMFENCE;                          \
    __builtin_amdgcn_s_waitcnt(0xC07F); MEMFENCE;                              \
    __builtin_amdgcn_s_setprio(1);                                             \
    _Pragma("unroll")                                                          \
    for (int mt = 0; mt < 4; mt++)                                             \
      _Pragma("unroll")                                                        \
      for (int nt = 0; nt < 4; nt++)                                           \
        acc[mt][nt] = __builtin_amdgcn_mfma_f32_16x16x32_bf16(af0[mt], bfr[nt], acc[mt][nt], 0, 0, 0); \
    __builtin_amdgcn_s_setprio(0);                                             \
    MEMFENCE; __builtin_amdgcn_s_barrier(); MEMFENCE;                          \
    _Pragma("unroll")                                                          \
    for (int mt = 0; mt < 4; mt++)                                             \
      af1[mt] = *(const bf16x8*)&sm[bb * 16384 + (wr * 128 + 64 + mt * 16 + lrow) * 32 + rslot]; \
    if (DOSTAGE) STAGE_B((TT) + 3);                                            \
    MEMFENCE; __builtin_amdgcn_s_barrier(); MEMFENCE;                          \
    __builtin_amdgcn_s_waitcnt(0xC07F); MEMFENCE;                              \
    __builtin_amdgcn_s_setprio(1);                                             \
    _Pragma("unroll")                                                          \
    for (int mt = 0; mt < 4; mt++)                                             \
      _Pragma("unroll")                                                        \
      for (int nt = 0; nt < 4; nt++)                                           \
        acc[4 + mt][nt] = __builtin_amdgcn_mfma_f32_16x16x32_bf16(af1[mt], bfr[nt], acc[4 + mt][nt], 0, 0, 0); \
    __builtin_amdgcn_s_setprio(0);                                             \
  } while (0)

#define GEMM_KLOOP()                                                           \
  STAGE_AB(0); STAGE_AB(1); STAGE_AB(2);                                       \
  for (int t = 0; t < 61; ++t) KSTEP(t, 0x0078, true);                         \
  KSTEP(61, 0x0078, false);                                                    \
  KSTEP(62, 0x0074, false);                                                    \
  KSTEP(63, 0x0070, false);

// ---------------- QKV GEMM + fused RoPE/relayout epilogue ----------------
__global__ __launch_bounds__(512, 2)
void gemm_qkv256(const __hip_bfloat16* __restrict__ A,
                 const __hip_bfloat16* __restrict__ W,
                 __hip_bfloat16* __restrict__ Qr,
                 __hip_bfloat16* __restrict__ Kr,
                 __hip_bfloat16* __restrict__ Vt)
{
  extern __shared__ __hip_bfloat16 sm[];   // 128KB: 4 bufs x (A 8192 + B 8192)
  GEMM_PREAMBLE(A, W)
  GEMM_KLOOP()

  // -------- epilogue: RoPE (Q/K) or transpose (V), via LDS restage --------
  const int seg = n0 >> 11;               // 0=Q 1=K 2=V
  const int h0 = (n0 & 2047) >> 7;
  const int b = m0 >> 11;
  const int seq0 = m0 & 2047;
  float* invfp = (float*)((char*)sm + 122880);

  __syncthreads();
  if (seg < 2 && tid < 64) invfp[tid] = __expf(-(float)tid * 0.14391156831212787f);

  const float qs = (seg == 0) ? 0.08838834764831845f : 1.0f;
  for (int p = 0; p < 2; ++p) {
    if (p) __syncthreads();
    if (wr == p) {
      if (seg < 2) {                      // Csh[row(128)][264]
#pragma unroll
        for (int mt = 0; mt < 8; mt++)
#pragma unroll
          for (int nt = 0; nt < 4; nt++)
#pragma unroll
            for (int r = 0; r < 4; r++)
              sm[(mt * 16 + lq4 + r) * 264 + wc * 64 + nt * 16 + lrow] =
                  __float2bfloat16(acc[mt][nt][r]);
      } else {                            // CshT[col(256)][136]
#pragma unroll
        for (int mt = 0; mt < 8; mt++)
#pragma unroll
          for (int nt = 0; nt < 4; nt++)
#pragma unroll
            for (int r = 0; r < 4; r++)
              sm[(wc * 64 + nt * 16 + lrow) * 136 + mt * 16 + lq4 + r] =
                  __float2bfloat16(acc[mt][nt][r]);
      }
    }
    __syncthreads();
    if (seg < 2) {
      __hip_bfloat16* Out = seg ? Kr : Qr;
#pragma unroll
      for (int it = 0; it < 4; ++it) {
        const int task = tid + it * 512;
        const int row = task >> 4;
        const int hh = (task >> 3) & 1;
        const int g8 = (task & 7) * 8;
        const int seq = seq0 + p * 128 + row;
        const float pos = (float)seq;
        const bf16x8 lo8 = *(const bf16x8*)&sm[row * 264 + hh * 128 + g8];
        const bf16x8 hi8 = *(const bf16x8*)&sm[row * 264 + hh * 128 + g8 + 64];
        alignas(16) __hip_bfloat16 lo[8], hi[8];
#pragma unroll
        for (int k = 0; k < 8; k++) {
          float sn, cs;
          __sincosf(pos * invfp[g8 + k], &sn, &cs);
          const float a = (float)lo8[k];
          const float bb2 = (float)hi8[k];
          lo[k] = __float2bfloat16((a * cs - bb2 * sn) * qs);
          hi[k] = __float2bfloat16((bb2 * cs + a * sn) * qs);
        }
        const size_t ob = ((size_t)((b * 16 + h0 + hh) * 2048 + seq)) * 128;
        *(bf16x8*)&Out[ob + g8] = *(const bf16x8*)lo;
        *(bf16x8*)&Out[ob + g8 + 64] = *(const bf16x8*)hi;
      }
    } else {
#pragma unroll
      for (int it = 0; it < 8; ++it) {
        const int task = tid + it * 512;
        const int col = task >> 4;
        const int sg = (task & 15) * 8;
        const bf16x8 v8 = *(const bf16x8*)&sm[col * 136 + sg];
        const int hh = col >> 7, d = col & 127;
        *(bf16x8*)&Vt[((size_t)((b * 16 + h0 + hh) * 128 + d)) * 2048 + seq0 + p * 128 + sg] = v8;
      }
    }
  }
}

// ---------------- O-proj GEMM: y[4096][2048] = A x Wo^T (fp32 out) ----------
__global__ __launch_bounds__(512, 2)
void gemm_o256(const __hip_bfloat16* __restrict__ A,
               const __hip_bfloat16* __restrict__ Wo,
               float* __restrict__ C)
{
  extern __shared__ __hip_bfloat16 sm[];
  GEMM_PREAMBLE(A, Wo)
  GEMM_KLOOP()
#pragma unroll
  for (int mt = 0; mt < 8; mt++)
#pragma unroll
    for (int nt = 0; nt < 4; nt++)
#pragma unroll
      for (int r = 0; r < 4; r++)
        C[(size_t)(m0 + wr * 128 + mt * 16 + lq4 + r) * 2048 +
          (n0 + wc * 64 + nt * 16 + lrow)] = acc[mt][nt][r];
}

#undef KSTEP
#undef GEMM_KLOOP
#undef STAGE_A
#undef STAGE_B
#undef STAGE_AB
#undef GEMM_PREAMBLE

// ---------------- sliding-window flash attention (unchanged) ----------------
#define KSTR 136
#define VSTR 72
__global__ __launch_bounds__(512, 4)
void attn_swa(const __hip_bfloat16* __restrict__ Qr, const __hip_bfloat16* __restrict__ Kr,
              const __hip_bfloat16* __restrict__ Vt, __hip_bfloat16* __restrict__ Out)
{
  __shared__ __hip_bfloat16 Ks[64 * KSTR];
  __shared__ __hip_bfloat16 Vs[128 * VSTR];
  __shared__ __hip_bfloat16 Pb[8][16 * VSTR];
  const int qt = blockIdx.x, bh = blockIdx.y;
  const int tid = threadIdx.x, lane = tid & 63, wave = tid >> 6;
  const int lrow = lane & 15, lk = (lane >> 4) * 8, lq4 = (lane >> 4) * 4;
  const int i0 = qt * 128;
  const float NEG_INF = -__builtin_inff();
  const __hip_bfloat16* Qh = Qr + (size_t)bh * 2048 * 128;
  const __hip_bfloat16* Kh = Kr + (size_t)bh * 2048 * 128;
  const __hip_bfloat16* Vh = Vt + (size_t)bh * 128 * 2048;

  const int ck0 = tid, ck1 = tid + 512;
  const int kr0 = ck0 >> 4, kg0 = (ck0 & 15) * 8;
  const int kr1 = ck1 >> 4, kg1 = (ck1 & 15) * 8;
  const int cv0 = tid, cv1 = tid + 512;
  const int vd0 = cv0 >> 3, vc0 = (cv0 & 7) * 8;
  const int vd1 = cv1 >> 3, vc1 = (cv1 & 7) * 8;

  const int iw = i0 + wave * 16 + lrow;
  bf16x8 qf[4];
#pragma unroll
  for (int ks = 0; ks < 4; ks++)
    qf[ks] = *(const bf16x8*)&Qh[(size_t)iw * 128 + ks * 32 + lk];

  floatx4 accO[8] = {};
  float m_i = NEG_INF, l_i = 0.f;
  const int imin = i0 + wave * 16;
  const int lo = i0 - 511;
  const int jt_lo = (lo > 0 ? lo : 0) >> 6;
  const int jt_hi = (i0 + 127) >> 6;

  int j0n = jt_lo * 64;
  int4 rk0 = *(const int4*)&Kh[(size_t)(j0n + kr0) * 128 + kg0];
  int4 rk1 = *(const int4*)&Kh[(size_t)(j0n + kr1) * 128 + kg1];
  int4 rv0 = *(const int4*)&Vh[(size_t)vd0 * 2048 + j0n + vc0];
  int4 rv1 = *(const int4*)&Vh[(size_t)vd1 * 2048 + j0n + vc1];

  for (int jt = jt_lo; jt <= jt_hi; jt++) {
    const int j0 = jt * 64;
    __syncthreads();
    *(int4*)&Ks[kr0 * KSTR + kg0] = rk0;
    *(int4*)&Ks[kr1 * KSTR + kg1] = rk1;
    *(int4*)&Vs[vd0 * VSTR + vc0] = rv0;
    *(int4*)&Vs[vd1 * VSTR + vc1] = rv1;
    if (jt < jt_hi) {
      const int jn = j0 + 64;
      rk0 = *(const int4*)&Kh[(size_t)(jn + kr0) * 128 + kg0];
      rk1 = *(const int4*)&Kh[(size_t)(jn + kr1) * 128 + kg1];
      rv0 = *(const int4*)&Vh[(size_t)vd0 * 2048 + jn + vc0];
      rv1 = *(const int4*)&Vh[(size_t)vd1 * 2048 + jn + vc1];
    }
    asm volatile("" ::: "memory");
    __builtin_amdgcn_s_waitcnt(0xC07F);
    __builtin_amdgcn_s_barrier();
    asm volatile("" ::: "memory");

    floatx4 s[4] = {};
#pragma unroll
    for (int nt = 0; nt < 4; nt++) {
      const int krow = (nt * 16 + lrow) * KSTR;
#pragma unroll
      for (int ks = 0; ks < 4; ks++) {
        const bf16x8 kf = *(const bf16x8*)&Ks[krow + ks * 32 + lk];
        s[nt] = __builtin_amdgcn_mfma_f32_16x16x32_bf16(kf, qf[ks], s[nt], 0, 0, 0);
      }
    }
    const bool full = (j0 + 63 <= imin) && (j0 >= imin + 15 - 511);
    float rmax = NEG_INF;
    if (full) {
#pragma unroll
      for (int nt = 0; nt < 4; nt++)
#pragma unroll
        for (int r = 0; r < 4; r++) rmax = fmaxf(rmax, s[nt][r]);
    } else {
#pragma unroll
      for (int nt = 0; nt < 4; nt++) {
#pragma unroll
        for (int r = 0; r < 4; r++) {
          const int j = j0 + nt * 16 + lq4 + r;
          const float sv = ((j <= iw) && (j > iw - 512)) ? s[nt][r] : NEG_INF;
          s[nt][r] = sv;
          rmax = fmaxf(rmax, sv);
        }
      }
    }
    rmax = fmaxf(rmax, __shfl_xor(rmax, 16));
    rmax = fmaxf(rmax, __shfl_xor(rmax, 32));
    const float mnew = fmaxf(m_i, rmax);
    const float alpha = __expf(fminf(m_i - mnew, 0.f));
    m_i = mnew;
    float rs = 0.f;
    if (full) {
#pragma unroll
      for (int nt = 0; nt < 4; nt++)
#pragma unroll
        for (int r = 0; r < 4; r++) {
          const float p = __expf(s[nt][r] - mnew);
          s[nt][r] = p;
          rs += p;
        }
    } else {
#pragma unroll
      for (int nt = 0; nt < 4; nt++)
#pragma unroll
        for (int r = 0; r < 4; r++) {
          const float sv = s[nt][r];
          const float p = (sv == NEG_INF) ? 0.f : __expf(sv - mnew);
          s[nt][r] = p;
          rs += p;
        }
    }
    rs += __shfl_xor(rs, 16);
    rs += __shfl_xor(rs, 32);
    l_i = l_i * alpha + rs;
#pragma unroll
    for (int dt = 0; dt < 8; dt++) accO[dt] *= alpha;
#pragma unroll
    for (int nt = 0; nt < 4; nt++) {
      alignas(8) __hip_bfloat16 p4[4];
#pragma unroll
      for (int r = 0; r < 4; r++) p4[r] = __float2bfloat16(s[nt][r]);
      *(uint64_t*)&Pb[wave][lrow * VSTR + nt * 16 + lq4] = *(const uint64_t*)p4;
    }
    bf16x8 pf[2];
#pragma unroll
    for (int jf = 0; jf < 2; jf++)
      pf[jf] = *(const bf16x8*)&Pb[wave][lrow * VSTR + jf * 32 + lk];
#pragma unroll
    for (int dt = 0; dt < 8; dt++) {
      const int vrow = (dt * 16 + lrow) * VSTR;
#pragma unroll
      for (int jf = 0; jf < 2; jf++) {
        const bf16x8 vf = *(const bf16x8*)&Vs[vrow + jf * 32 + lk];
        accO[dt] = __builtin_amdgcn_mfma_f32_16x16x32_bf16(vf, pf[jf], accO[dt], 0, 0, 0);
      }
    }
  }
  const int b = bh >> 4, h = bh & 15;
  const float inv_l = 1.0f / l_i;
  const size_t rowb = ((size_t)(b * 2048 + iw)) * 2048 + h * 128;
#pragma unroll
  for (int dt = 0; dt < 8; dt++) {
    alignas(8) __hip_bfloat16 o4[4];
#pragma unroll
    for (int r = 0; r < 4; r++) o4[r] = __float2bfloat16(accO[dt][r] * inv_l);
    *(uint64_t*)&Out[rowb + dt * 16 + lq4] = *(const uint64_t*)o4;
  }
}

// ---------------- launch ----------------
extern "C" void kernel_launch(void* const* d_in, const int* in_sizes, int n_in,
                              void* d_out, int out_size, void* d_ws, size_t ws_size,
                              hipStream_t stream)
{
  const float* x = (const float*)d_in[0];      // [2,2048,2048]
  const float* w_qkv = (const float*)d_in[1];  // [6144,2048]
  const float* w_o = (const float*)d_in[2];    // [2048,2048]
  float* y = (float*)d_out;                    // [2,2048,2048] fp32
  char* ws = (char*)d_ws;

  const size_t SZ_X = 16777216;     // 4096*2048*2 B
  const size_t SZ_WQKV = 25165824;  // 6144*2048*2 B
  const size_t SZ_Q = 16777216;     // 32*2048*128*2 B

  __hip_bfloat16* xb = (__hip_bfloat16*)(ws);            // x bf16; later attn out
  __hip_bfloat16* wqkvb = (__hip_bfloat16*)(ws + SZ_X);  // w_qkv bf16; later w_o bf16
  __hip_bfloat16* Qr = (__hip_bfloat16*)(ws + SZ_X + SZ_WQKV);
  __hip_bfloat16* Kr = (__hip_bfloat16*)(ws + SZ_X + SZ_WQKV + SZ_Q);
  __hip_bfloat16* Vt = (__hip_bfloat16*)(ws + SZ_X + SZ_WQKV + 2 * SZ_Q);

  static bool s_attr_done = false;
  if (!s_attr_done) {
    hipFuncSetAttribute((const void*)gemm_qkv256,
                        hipFuncAttributeMaxDynamicSharedMemorySize, 131072);
    hipFuncSetAttribute((const void*)gemm_o256,
                        hipFuncAttributeMaxDynamicSharedMemorySize, 131072);
    s_attr_done = true;
  }

  cvt_kernel<<<dim3(8192), dim3(256), 0, stream>>>(x, xb, 8388608);
  cvt_kernel<<<dim3(12288), dim3(256), 0, stream>>>(w_qkv, wqkvb, 12582912);
  gemm_qkv256<<<dim3(16, 24), dim3(512), 131072, stream>>>(xb, wqkvb, Qr, Kr, Vt);
  attn_swa<<<dim3(16, 32), dim3(512), 0, stream>>>(Qr, Kr, Vt, xb /*attn_out*/);
  cvt_kernel<<<dim3(4096), dim3(256), 0, stream>>>(w_o, wqkvb, 4194304);
  gemm_o256<<<dim3(16, 8), dim3(512), 131072, stream>>>(xb, wqkvb, y);
}

// Round 5
// 338.902 us; speedup vs baseline: 1.1374x; 1.0657x over previous
//
#include <hip/hip_runtime.h>
#include <hip/hip_bf16.h>
#include <cstdint>

typedef __bf16 bf16x8 __attribute__((ext_vector_type(8)));
typedef float floatx4 __attribute__((ext_vector_type(4)));

__device__ __forceinline__ void gl2lds16(const void* g, void* l) {
  __builtin_amdgcn_global_load_lds(
      (const __attribute__((address_space(1))) unsigned int*)g,
      (__attribute__((address_space(3))) unsigned int*)(uintptr_t)l,
      16, 0, 0);
}

// ---------------- fp32 -> bf16 convert ----------------
__global__ __launch_bounds__(256)
void cvt_kernel(const float* __restrict__ in, __hip_bfloat16* __restrict__ out, int n) {
  int i = (blockIdx.x * 256 + threadIdx.x) * 4;
  if (i >= n) return;
  const float4 v = *(const float4*)(in + i);
  out[i + 0] = __float2bfloat16(v.x);
  out[i + 1] = __float2bfloat16(v.y);
  out[i + 2] = __float2bfloat16(v.z);
  out[i + 3] = __float2bfloat16(v.w);
}

// fused cvt of x (n0 elems) and w_qkv into one contiguous bf16 output
__global__ __launch_bounds__(256)
void cvt2_kernel(const float* __restrict__ in0, const float* __restrict__ in1,
                 __hip_bfloat16* __restrict__ out, int n0, int ntot) {
  int i = (blockIdx.x * 256 + threadIdx.x) * 4;
  if (i >= ntot) return;
  const float4 v = (i < n0) ? *(const float4*)(in0 + i)
                            : *(const float4*)(in1 + (i - n0));
  out[i + 0] = __float2bfloat16(v.x);
  out[i + 1] = __float2bfloat16(v.y);
  out[i + 2] = __float2bfloat16(v.z);
  out[i + 3] = __float2bfloat16(v.w);
}

#define MEMFENCE asm volatile("" ::: "memory")

// ================= 256x256 QKV GEMM (R2 single-barrier K-loop) =================
// 8 waves (2M x 4N); quad-buffer BK=32, depth-3 prefetch; counted vmcnt (never
// 0 in steady loop); 1 barrier / K-step. XOR granule swizzle: LDS slot s of
// row r holds source granule s ^ ((r>>1)&3).
__global__ __launch_bounds__(512, 2)
void gemm_qkv256(const __hip_bfloat16* __restrict__ A,
                 const __hip_bfloat16* __restrict__ W,
                 __hip_bfloat16* __restrict__ Qr,
                 __hip_bfloat16* __restrict__ Kr,
                 __hip_bfloat16* __restrict__ Vt)
{
  extern __shared__ __hip_bfloat16 sm[];   // 128KB: 4 bufs x (A 8192 + B 8192)
  const int tid = threadIdx.x, lane = tid & 63, wave = tid >> 6;
  const int wr = wave >> 2, wc = wave & 3;
  const int m0 = blockIdx.x << 8, n0 = blockIdx.y << 8;
  const int lrow = lane & 15, dg = lane >> 4, lq4 = dg * 4;
  const int rslot = (dg ^ ((lrow >> 1) & 3)) * 8;
  const int arow = tid >> 2;
  const int ascol = ((tid & 3) ^ ((tid >> 3) & 3)) * 8;
  const __hip_bfloat16* aS0 = A + (size_t)(m0 + arow) * 2048 + ascol;
  const __hip_bfloat16* aS1 = A + (size_t)(m0 + 128 + arow) * 2048 + ascol;
  const __hip_bfloat16* bS0 = W + (size_t)(n0 + arow) * 2048 + ascol;
  const __hip_bfloat16* bS1 = W + (size_t)(n0 + 128 + arow) * 2048 + ascol;
  floatx4 acc[8][4] = {};

#define QSTAGE(TT) do { const int bb_ = (TT) & 3; const int kk_ = (TT) * 32;   \
    gl2lds16(aS0 + kk_, &sm[bb_ * 16384 + tid * 8]);                           \
    gl2lds16(aS1 + kk_, &sm[bb_ * 16384 + 4096 + tid * 8]);                    \
    gl2lds16(bS0 + kk_, &sm[bb_ * 16384 + 8192 + tid * 8]);                    \
    gl2lds16(bS1 + kk_, &sm[bb_ * 16384 + 12288 + tid * 8]); } while (0)

#define QKSTEP(TT, WIMM, DOSTAGE) do {                                         \
    MEMFENCE; __builtin_amdgcn_s_waitcnt(WIMM); MEMFENCE;                      \
    __builtin_amdgcn_s_barrier(); MEMFENCE;                                    \
    const int bb = (TT) & 3;                                                   \
    if (DOSTAGE) QSTAGE((TT) + 3);                                             \
    bf16x8 af[8], bfr[4];                                                      \
    _Pragma("unroll")                                                          \
    for (int mt = 0; mt < 8; mt++)                                             \
      af[mt] = *(const bf16x8*)&sm[bb * 16384 + (wr * 128 + mt * 16 + lrow) * 32 + rslot]; \
    _Pragma("unroll")                                                          \
    for (int nt = 0; nt < 4; nt++)                                             \
      bfr[nt] = *(const bf16x8*)&sm[bb * 16384 + 8192 + (wc * 64 + nt * 16 + lrow) * 32 + rslot]; \
    __builtin_amdgcn_s_setprio(1);                                             \
    _Pragma("unroll")                                                          \
    for (int mt = 0; mt < 8; mt++)                                             \
      _Pragma("unroll")                                                        \
      for (int nt = 0; nt < 4; nt++)                                           \
        acc[mt][nt] = __builtin_amdgcn_mfma_f32_16x16x32_bf16(af[mt], bfr[nt], acc[mt][nt], 0, 0, 0); \
    __builtin_amdgcn_s_setprio(0);                                             \
  } while (0)

  QSTAGE(0); QSTAGE(1); QSTAGE(2);   // 12 VMEM in flight
  // 0x0078=vmcnt(8)lgkm(0)  0x0074=vmcnt(4)  0x0070=vmcnt(0)
  for (int t = 0; t < 61; ++t) QKSTEP(t, 0x0078, true);
  QKSTEP(61, 0x0078, false);
  QKSTEP(62, 0x0074, false);
  QKSTEP(63, 0x0070, false);
#undef QKSTEP
#undef QSTAGE

  // -------- epilogue: RoPE (Q/K) or transpose (V), via LDS restage --------
  const int seg = n0 >> 11;               // 0=Q 1=K 2=V
  const int h0 = (n0 & 2047) >> 7;
  const int b = m0 >> 11;
  const int seq0 = m0 & 2047;
  float* invfp = (float*)((char*)sm + 122880);

  __syncthreads();
  if (seg < 2 && tid < 64) invfp[tid] = __expf(-(float)tid * 0.14391156831212787f);

  const float qs = (seg == 0) ? 0.08838834764831845f : 1.0f;
  for (int p = 0; p < 2; ++p) {
    if (p) __syncthreads();
    if (wr == p) {
      if (seg < 2) {                      // Csh[row(128)][264]
#pragma unroll
        for (int mt = 0; mt < 8; mt++)
#pragma unroll
          for (int nt = 0; nt < 4; nt++)
#pragma unroll
            for (int r = 0; r < 4; r++)
              sm[(mt * 16 + lq4 + r) * 264 + wc * 64 + nt * 16 + lrow] =
                  __float2bfloat16(acc[mt][nt][r]);
      } else {                            // CshT[col(256)][136]
#pragma unroll
        for (int mt = 0; mt < 8; mt++)
#pragma unroll
          for (int nt = 0; nt < 4; nt++)
#pragma unroll
            for (int r = 0; r < 4; r++)
              sm[(wc * 64 + nt * 16 + lrow) * 136 + mt * 16 + lq4 + r] =
                  __float2bfloat16(acc[mt][nt][r]);
      }
    }
    __syncthreads();
    if (seg < 2) {
      __hip_bfloat16* Out = seg ? Kr : Qr;
#pragma unroll
      for (int it = 0; it < 4; ++it) {
        const int task = tid + it * 512;
        const int row = task >> 4;
        const int hh = (task >> 3) & 1;
        const int g8 = (task & 7) * 8;
        const int seq = seq0 + p * 128 + row;
        const float pos = (float)seq;
        const bf16x8 lo8 = *(const bf16x8*)&sm[row * 264 + hh * 128 + g8];
        const bf16x8 hi8 = *(const bf16x8*)&sm[row * 264 + hh * 128 + g8 + 64];
        alignas(16) __hip_bfloat16 lo[8], hi[8];
#pragma unroll
        for (int k = 0; k < 8; k++) {
          float sn, cs;
          __sincosf(pos * invfp[g8 + k], &sn, &cs);
          const float a = (float)lo8[k];
          const float bb2 = (float)hi8[k];
          lo[k] = __float2bfloat16((a * cs - bb2 * sn) * qs);
          hi[k] = __float2bfloat16((bb2 * cs + a * sn) * qs);
        }
        const size_t ob = ((size_t)((b * 16 + h0 + hh) * 2048 + seq)) * 128;
        *(bf16x8*)&Out[ob + g8] = *(const bf16x8*)lo;
        *(bf16x8*)&Out[ob + g8 + 64] = *(const bf16x8*)hi;
      }
    } else {
#pragma unroll
      for (int it = 0; it < 8; ++it) {
        const int task = tid + it * 512;
        const int col = task >> 4;
        const int sg = (task & 15) * 8;
        const bf16x8 v8 = *(const bf16x8*)&sm[col * 136 + sg];
        const int hh = col >> 7, d = col & 127;
        *(bf16x8*)&Vt[((size_t)((b * 16 + h0 + hh) * 128 + d)) * 2048 + seq0 + p * 128 + sg] = v8;
      }
    }
  }
}

// ============ O-proj GEMM: 256M x 128N tile -> grid 16x16 = 256 blocks ========
// Same machinery, 3 staging granules/thread/K-step -> vmcnt(6)/3/0.
// Per-wave 128x32 output: acc[8][2].
__global__ __launch_bounds__(512, 2)
void gemm_o256(const __hip_bfloat16* __restrict__ A,
               const __hip_bfloat16* __restrict__ Wo,
               float* __restrict__ C)
{
  extern __shared__ __hip_bfloat16 sm[];   // 96KB: 4 bufs x (A 8192 + B 4096)
  const int tid = threadIdx.x, lane = tid & 63, wave = tid >> 6;
  const int wr = wave >> 2, wc = wave & 3;
  const int m0 = blockIdx.x << 8, n0 = blockIdx.y << 7;
  const int lrow = lane & 15, dg = lane >> 4, lq4 = dg * 4;
  const int rslot = (dg ^ ((lrow >> 1) & 3)) * 8;
  const int arow = tid >> 2;
  const int ascol = ((tid & 3) ^ ((tid >> 3) & 3)) * 8;
  const __hip_bfloat16* aS0 = A + (size_t)(m0 + arow) * 2048 + ascol;
  const __hip_bfloat16* aS1 = A + (size_t)(m0 + 128 + arow) * 2048 + ascol;
  const __hip_bfloat16* bS0 = Wo + (size_t)(n0 + arow) * 2048 + ascol;
  floatx4 acc[8][2] = {};

#define OSTAGE(TT) do { const int bb_ = (TT) & 3; const int kk_ = (TT) * 32;   \
    gl2lds16(aS0 + kk_, &sm[bb_ * 12288 + tid * 8]);                           \
    gl2lds16(aS1 + kk_, &sm[bb_ * 12288 + 4096 + tid * 8]);                    \
    gl2lds16(bS0 + kk_, &sm[bb_ * 12288 + 8192 + tid * 8]); } while (0)

#define OKSTEP(TT, WIMM, DOSTAGE) do {                                         \
    MEMFENCE; __builtin_amdgcn_s_waitcnt(WIMM); MEMFENCE;                      \
    __builtin_amdgcn_s_barrier(); MEMFENCE;                                    \
    const int bb = (TT) & 3;                                                   \
    if (DOSTAGE) OSTAGE((TT) + 3);                                             \
    bf16x8 af[8], bfr[2];                                                      \
    _Pragma("unroll")                                                          \
    for (int mt = 0; mt < 8; mt++)                                             \
      af[mt] = *(const bf16x8*)&sm[bb * 12288 + (wr * 128 + mt * 16 + lrow) * 32 + rslot]; \
    _Pragma("unroll")                                                          \
    for (int nt = 0; nt < 2; nt++)                                             \
      bfr[nt] = *(const bf16x8*)&sm[bb * 12288 + 8192 + (wc * 32 + nt * 16 + lrow) * 32 + rslot]; \
    __builtin_amdgcn_s_setprio(1);                                             \
    _Pragma("unroll")                                                          \
    for (int mt = 0; mt < 8; mt++)                                             \
      _Pragma("unroll")                                                        \
      for (int nt = 0; nt < 2; nt++)                                           \
        acc[mt][nt] = __builtin_amdgcn_mfma_f32_16x16x32_bf16(af[mt], bfr[nt], acc[mt][nt], 0, 0, 0); \
    __builtin_amdgcn_s_setprio(0);                                             \
  } while (0)

  OSTAGE(0); OSTAGE(1); OSTAGE(2);   // 9 VMEM in flight
  // 0x0076=vmcnt(6)lgkm(0)  0x0073=vmcnt(3)  0x0070=vmcnt(0)
  for (int t = 0; t < 61; ++t) OKSTEP(t, 0x0076, true);
  OKSTEP(61, 0x0076, false);
  OKSTEP(62, 0x0073, false);
  OKSTEP(63, 0x0070, false);
#undef OKSTEP
#undef OSTAGE

#pragma unroll
  for (int mt = 0; mt < 8; mt++)
#pragma unroll
    for (int nt = 0; nt < 2; nt++)
#pragma unroll
      for (int r = 0; r < 4; r++)
        C[(size_t)(m0 + wr * 128 + mt * 16 + lq4 + r) * 2048 +
          (n0 + wc * 32 + nt * 16 + lrow)] = acc[mt][nt][r];
}

// ---------------- sliding-window flash attention (unchanged) ----------------
#define KSTR 136
#define VSTR 72
__global__ __launch_bounds__(512, 4)
void attn_swa(const __hip_bfloat16* __restrict__ Qr, const __hip_bfloat16* __restrict__ Kr,
              const __hip_bfloat16* __restrict__ Vt, __hip_bfloat16* __restrict__ Out)
{
  __shared__ __hip_bfloat16 Ks[64 * KSTR];
  __shared__ __hip_bfloat16 Vs[128 * VSTR];
  __shared__ __hip_bfloat16 Pb[8][16 * VSTR];
  const int qt = blockIdx.x, bh = blockIdx.y;
  const int tid = threadIdx.x, lane = tid & 63, wave = tid >> 6;
  const int lrow = lane & 15, lk = (lane >> 4) * 8, lq4 = (lane >> 4) * 4;
  const int i0 = qt * 128;
  const float NEG_INF = -__builtin_inff();
  const __hip_bfloat16* Qh = Qr + (size_t)bh * 2048 * 128;
  const __hip_bfloat16* Kh = Kr + (size_t)bh * 2048 * 128;
  const __hip_bfloat16* Vh = Vt + (size_t)bh * 128 * 2048;

  const int ck0 = tid, ck1 = tid + 512;
  const int kr0 = ck0 >> 4, kg0 = (ck0 & 15) * 8;
  const int kr1 = ck1 >> 4, kg1 = (ck1 & 15) * 8;
  const int cv0 = tid, cv1 = tid + 512;
  const int vd0 = cv0 >> 3, vc0 = (cv0 & 7) * 8;
  const int vd1 = cv1 >> 3, vc1 = (cv1 & 7) * 8;

  const int iw = i0 + wave * 16 + lrow;
  bf16x8 qf[4];
#pragma unroll
  for (int ks = 0; ks < 4; ks++)
    qf[ks] = *(const bf16x8*)&Qh[(size_t)iw * 128 + ks * 32 + lk];

  floatx4 accO[8] = {};
  float m_i = NEG_INF, l_i = 0.f;
  const int imin = i0 + wave * 16;
  const int lo = i0 - 511;
  const int jt_lo = (lo > 0 ? lo : 0) >> 6;
  const int jt_hi = (i0 + 127) >> 6;

  int j0n = jt_lo * 64;
  int4 rk0 = *(const int4*)&Kh[(size_t)(j0n + kr0) * 128 + kg0];
  int4 rk1 = *(const int4*)&Kh[(size_t)(j0n + kr1) * 128 + kg1];
  int4 rv0 = *(const int4*)&Vh[(size_t)vd0 * 2048 + j0n + vc0];
  int4 rv1 = *(const int4*)&Vh[(size_t)vd1 * 2048 + j0n + vc1];

  for (int jt = jt_lo; jt <= jt_hi; jt++) {
    const int j0 = jt * 64;
    __syncthreads();
    *(int4*)&Ks[kr0 * KSTR + kg0] = rk0;
    *(int4*)&Ks[kr1 * KSTR + kg1] = rk1;
    *(int4*)&Vs[vd0 * VSTR + vc0] = rv0;
    *(int4*)&Vs[vd1 * VSTR + vc1] = rv1;
    if (jt < jt_hi) {
      const int jn = j0 + 64;
      rk0 = *(const int4*)&Kh[(size_t)(jn + kr0) * 128 + kg0];
      rk1 = *(const int4*)&Kh[(size_t)(jn + kr1) * 128 + kg1];
      rv0 = *(const int4*)&Vh[(size_t)vd0 * 2048 + jn + vc0];
      rv1 = *(const int4*)&Vh[(size_t)vd1 * 2048 + jn + vc1];
    }
    asm volatile("" ::: "memory");
    __builtin_amdgcn_s_waitcnt(0xC07F);
    __builtin_amdgcn_s_barrier();
    asm volatile("" ::: "memory");

    floatx4 s[4] = {};
#pragma unroll
    for (int nt = 0; nt < 4; nt++) {
      const int krow = (nt * 16 + lrow) * KSTR;
#pragma unroll
      for (int ks = 0; ks < 4; ks++) {
        const bf16x8 kf = *(const bf16x8*)&Ks[krow + ks * 32 + lk];
        s[nt] = __builtin_amdgcn_mfma_f32_16x16x32_bf16(kf, qf[ks], s[nt], 0, 0, 0);
      }
    }
    const bool full = (j0 + 63 <= imin) && (j0 >= imin + 15 - 511);
    float rmax = NEG_INF;
    if (full) {
#pragma unroll
      for (int nt = 0; nt < 4; nt++)
#pragma unroll
        for (int r = 0; r < 4; r++) rmax = fmaxf(rmax, s[nt][r]);
    } else {
#pragma unroll
      for (int nt = 0; nt < 4; nt++) {
#pragma unroll
        for (int r = 0; r < 4; r++) {
          const int j = j0 + nt * 16 + lq4 + r;
          const float sv = ((j <= iw) && (j > iw - 512)) ? s[nt][r] : NEG_INF;
          s[nt][r] = sv;
          rmax = fmaxf(rmax, sv);
        }
      }
    }
    rmax = fmaxf(rmax, __shfl_xor(rmax, 16));
    rmax = fmaxf(rmax, __shfl_xor(rmax, 32));
    const float mnew = fmaxf(m_i, rmax);
    const float alpha = __expf(fminf(m_i - mnew, 0.f));
    m_i = mnew;
    float rs = 0.f;
    if (full) {
#pragma unroll
      for (int nt = 0; nt < 4; nt++)
#pragma unroll
        for (int r = 0; r < 4; r++) {
          const float p = __expf(s[nt][r] - mnew);
          s[nt][r] = p;
          rs += p;
        }
    } else {
#pragma unroll
      for (int nt = 0; nt < 4; nt++)
#pragma unroll
        for (int r = 0; r < 4; r++) {
          const float sv = s[nt][r];
          const float p = (sv == NEG_INF) ? 0.f : __expf(sv - mnew);
          s[nt][r] = p;
          rs += p;
        }
    }
    rs += __shfl_xor(rs, 16);
    rs += __shfl_xor(rs, 32);
    l_i = l_i * alpha + rs;
#pragma unroll
    for (int dt = 0; dt < 8; dt++) accO[dt] *= alpha;
#pragma unroll
    for (int nt = 0; nt < 4; nt++) {
      alignas(8) __hip_bfloat16 p4[4];
#pragma unroll
      for (int r = 0; r < 4; r++) p4[r] = __float2bfloat16(s[nt][r]);
      *(uint64_t*)&Pb[wave][lrow * VSTR + nt * 16 + lq4] = *(const uint64_t*)p4;
    }
    bf16x8 pf[2];
#pragma unroll
    for (int jf = 0; jf < 2; jf++)
      pf[jf] = *(const bf16x8*)&Pb[wave][lrow * VSTR + jf * 32 + lk];
#pragma unroll
    for (int dt = 0; dt < 8; dt++) {
      const int vrow = (dt * 16 + lrow) * VSTR;
#pragma unroll
      for (int jf = 0; jf < 2; jf++) {
        const bf16x8 vf = *(const bf16x8*)&Vs[vrow + jf * 32 + lk];
        accO[dt] = __builtin_amdgcn_mfma_f32_16x16x32_bf16(vf, pf[jf], accO[dt], 0, 0, 0);
      }
    }
  }
  const int b = bh >> 4, h = bh & 15;
  const float inv_l = 1.0f / l_i;
  const size_t rowb = ((size_t)(b * 2048 + iw)) * 2048 + h * 128;
#pragma unroll
  for (int dt = 0; dt < 8; dt++) {
    alignas(8) __hip_bfloat16 o4[4];
#pragma unroll
    for (int r = 0; r < 4; r++) o4[r] = __float2bfloat16(accO[dt][r] * inv_l);
    *(uint64_t*)&Out[rowb + dt * 16 + lq4] = *(const uint64_t*)o4;
  }
}

// ---------------- launch ----------------
extern "C" void kernel_launch(void* const* d_in, const int* in_sizes, int n_in,
                              void* d_out, int out_size, void* d_ws, size_t ws_size,
                              hipStream_t stream)
{
  const float* x = (const float*)d_in[0];      // [2,2048,2048]
  const float* w_qkv = (const float*)d_in[1];  // [6144,2048]
  const float* w_o = (const float*)d_in[2];    // [2048,2048]
  float* y = (float*)d_out;                    // [2,2048,2048] fp32
  char* ws = (char*)d_ws;

  const size_t SZ_X = 16777216;     // 4096*2048*2 B
  const size_t SZ_WQKV = 25165824;  // 6144*2048*2 B
  const size_t SZ_Q = 16777216;     // 32*2048*128*2 B

  __hip_bfloat16* xb = (__hip_bfloat16*)(ws);            // x bf16; later attn out
  __hip_bfloat16* wqkvb = (__hip_bfloat16*)(ws + SZ_X);  // w_qkv bf16; later w_o bf16
  __hip_bfloat16* Qr = (__hip_bfloat16*)(ws + SZ_X + SZ_WQKV);
  __hip_bfloat16* Kr = (__hip_bfloat16*)(ws + SZ_X + SZ_WQKV + SZ_Q);
  __hip_bfloat16* Vt = (__hip_bfloat16*)(ws + SZ_X + SZ_WQKV + 2 * SZ_Q);

  static bool s_attr_done = false;
  if (!s_attr_done) {
    hipFuncSetAttribute((const void*)gemm_qkv256,
                        hipFuncAttributeMaxDynamicSharedMemorySize, 131072);
    hipFuncSetAttribute((const void*)gemm_o256,
                        hipFuncAttributeMaxDynamicSharedMemorySize, 98304);
    s_attr_done = true;
  }

  // x + w_qkv converted in one launch (outputs are contiguous in ws)
  cvt2_kernel<<<dim3(20480), dim3(256), 0, stream>>>(x, w_qkv, xb, 8388608, 20971520);
  gemm_qkv256<<<dim3(16, 24), dim3(512), 131072, stream>>>(xb, wqkvb, Qr, Kr, Vt);
  attn_swa<<<dim3(16, 32), dim3(512), 0, stream>>>(Qr, Kr, Vt, xb /*attn_out*/);
  cvt_kernel<<<dim3(4096), dim3(256), 0, stream>>>(w_o, wqkvb, 4194304);
  gemm_o256<<<dim3(16, 16), dim3(512), 98304, stream>>>(xb, wqkvb, y);
}